// Round 9
// baseline (1464.691 us; speedup 1.0000x reference)
//
#include <hip/hip_runtime.h>
#include <math.h>

#define BB 8
#define NN 4096
#define CC 256
#define DD 64
#define MM 1024
#define KNB 16
#define OC 259

typedef unsigned long long ull;

// ---------------------------------------------------------------------------
// PHASE 1: blk 0-7 FPS | 8-519 G2 GEMM (self-scaled aw1, no prep dep) |
// 520 prep | 521-536 W12 | 537-2584 transpose. fps dominates (~684us); all
// other roles run concurrently on the remaining CUs.
__global__ __launch_bounds__(256) void phase1(
    const float* __restrict__ verts, const float* __restrict__ fm,
    const float* __restrict__ pw1, const float* __restrict__ pb1,
    const float* __restrict__ g1, const float* __restrict__ bb1,
    const float* __restrict__ m1, const float* __restrict__ v1,
    const float* __restrict__ pw2, const float* __restrict__ aw1,
    const float* __restrict__ g2v, const float* __restrict__ bb2,
    const float* __restrict__ m2, const float* __restrict__ v2,
    const float* __restrict__ ab1,
    float* __restrict__ fm_t, int* __restrict__ fpsi, float* __restrict__ G2,
    float* __restrict__ w1f, float* __restrict__ b1f, float* __restrict__ ab1f,
    float* __restrict__ aw1t, float* __restrict__ W12t) {
  __shared__ __align__(16) char smem[53440];
  int blk = blockIdx.x;
  int tid = threadIdx.x;

  if (blk < 8) {
    // ---- FPS (verbatim proven 675-684us version): 256 thr, 16 pts/thread,
    // reference-exact (p-c)^2 dist, two-pass DPP reduce, u64 parity slots,
    // depth-2 tree, no global stores in the loop.
    float* lx = (float*)smem;
    float* ly = lx + NN;
    float* lz = ly + NN;
    int* fps_l = (int*)(lz + NN);
    ull* wres = (ull*)(fps_l + MM);  // [2][4]
    int b = blk;
    const float* vb = verts + (size_t)b * 3 * NN;
    float px[16], py[16], pz[16], dist[16];
#pragma unroll
    for (int r = 0; r < 16; ++r) {
      int j = tid + r * 256;
      px[r] = vb[j]; py[r] = vb[NN + j]; pz[r] = vb[2 * NN + j];
      lx[j] = px[r]; ly[j] = py[r]; lz[j] = pz[r];
      dist[r] = 1e10f;
    }
    __syncthreads();
    int far = 0;
    for (int s = 0; s < MM; ++s) {
      if (tid == 0) fps_l[s] = far;
      if (s == MM - 1) break;
      float cx = lx[far], cy = ly[far], cz = lz[far];
      float vmax = -1.0f;
#pragma unroll
      for (int r = 0; r < 16; ++r) {
        float dx = px[r] - cx, dy = py[r] - cy, dz = pz[r] - cz;
        float d = dx * dx + dy * dy + dz * dz;
        dist[r] = fminf(dist[r], d);
        vmax = fmaxf(vmax, dist[r]);
      }
#define VRED(CTRL)                                                            \
      {                                                                       \
        int o = __builtin_amdgcn_update_dpp(__float_as_int(vmax),             \
                                            __float_as_int(vmax), CTRL, 0xF,  \
                                            0xF, false);                      \
        vmax = fmaxf(vmax, __int_as_float(o));                                \
      }
      VRED(0x111) VRED(0x112) VRED(0x114) VRED(0x118) VRED(0x142) VRED(0x143)
#undef VRED
      float svmax =
          __int_as_float(__builtin_amdgcn_readlane(__float_as_int(vmax), 63));
      int minj = 0x7FFFFFFF;
#pragma unroll
      for (int r = 0; r < 16; ++r) {
        int cand = (dist[r] == svmax) ? (tid + r * 256) : 0x7FFFFFFF;
        minj = (cand < minj) ? cand : minj;
      }
#define IRED(CTRL)                                                            \
      {                                                                       \
        int o = __builtin_amdgcn_update_dpp(minj, minj, CTRL, 0xF, 0xF,       \
                                            false);                          \
        minj = (o < minj) ? o : minj;                                         \
      }
      IRED(0x111) IRED(0x112) IRED(0x114) IRED(0x118) IRED(0x142) IRED(0x143)
#undef IRED
      if ((tid & 63) == 63)
        wres[(s & 1) * 4 + (tid >> 6)] =
            ((ull)(unsigned)__float_as_int(svmax) << 12) |
            (ull)(4095 - minj);
      __syncthreads();
      int p = s & 1;
      ull k0 = wres[p * 4 + 0], k1 = wres[p * 4 + 1];
      ull k2 = wres[p * 4 + 2], k3 = wres[p * 4 + 3];
      ull a = (k0 > k1) ? k0 : k1;
      ull c = (k2 > k3) ? k2 : k3;
      a = (c > a) ? c : a;
      far = 4095 - (int)(a & 0xFFFull);
    }
    __syncthreads();
    for (int x = tid; x < MM; x += 256) fpsi[b * MM + x] = fps_l[x];

  } else if (blk < 520) {
    // ---- G2[b][n][d] = sum_c (aw1[d][c]*s2[d]) * fm[b][c][n]
    float (*a_l)[68] = (float(*)[68])smem;
    float (*b_l)[68] = (float(*)[68])(smem + 64 * 68 * 4);
    int t = blk - 8;
    int b = t >> 6;
    int n0 = (t & 63) * 64;
    int rr = tid >> 4, q4 = tid & 15;
    float s2v[4];
#pragma unroll
    for (int j = 0; j < 4; ++j)
      s2v[j] = g2v[q4 * 4 + j] * rsqrtf(v2[q4 * 4 + j] + 1e-5f);
    float acc[4][4];
#pragma unroll
    for (int q = 0; q < 4; ++q)
#pragma unroll
      for (int x = 0; x < 4; ++x) acc[q][x] = 0.f;
    for (int c0 = 0; c0 < 256; c0 += 64) {
      __syncthreads();
#pragma unroll
      for (int rep = 0; rep < 4; ++rep) {
        int cc = rr + rep * 16;
        *(float4*)&a_l[cc][q4 * 4] =
            *(const float4*)&fm[((size_t)b * CC + c0 + cc) * NN + n0 + q4 * 4];
        float bv[4];
#pragma unroll
        for (int j = 0; j < 4; ++j)
          bv[j] = aw1[(q4 * 4 + j) * 256 + c0 + cc] * s2v[j];
        *(float4*)&b_l[cc][q4 * 4] = make_float4(bv[0], bv[1], bv[2], bv[3]);
      }
      __syncthreads();
#pragma unroll 8
      for (int kk = 0; kk < 64; ++kk) {
        float4 a4 = *(const float4*)&a_l[kk][rr * 4];
        float4 b4 = *(const float4*)&b_l[kk][q4 * 4];
        float av[4] = {a4.x, a4.y, a4.z, a4.w};
#pragma unroll
        for (int q = 0; q < 4; ++q) {
          acc[q][0] += av[q] * b4.x;
          acc[q][1] += av[q] * b4.y;
          acc[q][2] += av[q] * b4.z;
          acc[q][3] += av[q] * b4.w;
        }
      }
    }
#pragma unroll
    for (int q = 0; q < 4; ++q)
      *(float4*)&G2[((size_t)b * NN + n0 + rr * 4 + q) * 64 + q4 * 4] =
          make_float4(acc[q][0], acc[q][1], acc[q][2], acc[q][3]);

  } else if (blk == 520) {
    // ---- small weight prep (BN folds; aw1t for fuse's vm stage)
    if (tid < 64) {
      float s = g1[tid] * rsqrtf(v1[tid] + 1e-5f);
      w1f[tid * 4 + 0] = pw1[tid * 3 + 0] * s;
      w1f[tid * 4 + 1] = pw1[tid * 3 + 1] * s;
      w1f[tid * 4 + 2] = pw1[tid * 3 + 2] * s;
      w1f[tid * 4 + 3] = 0.f;
      b1f[tid] = (pb1[tid] - m1[tid]) * s + bb1[tid];
      float s2 = g2v[tid] * rsqrtf(v2[tid] + 1e-5f);
      ab1f[tid] = (ab1[tid] - m2[tid]) * s2 + bb2[tid];
    }
    for (int x = tid; x < 256 * 64; x += 256) {
      int c = x >> 6, d = x & 63;
      float s2 = g2v[d] * rsqrtf(v2[d] + 1e-5f);
      aw1t[x] = aw1[d * 256 + c] * s2;
    }

  } else if (blk < 537) {
    // ---- W12t[i][d] = sum_c pw2[c][i]*aw1[d][c]*s2[d]
    int i = tid & 63;
    int d = (blk - 521) * 4 + (tid >> 6);
    float s2 = g2v[d] * rsqrtf(v2[d] + 1e-5f);
    const float* arow = aw1 + d * 256;
    float s = 0.f;
#pragma unroll 4
    for (int c = 0; c < 256; ++c) s += pw2[c * 64 + i] * arow[c];
    W12t[i * 64 + d] = s * s2;

  } else {
    // ---- transpose feature_map (B,C,N) -> (B,N,C)
    float (*tile)[65] = (float(*)[65])smem;
    int rb = blk - 537;
    int b = rb >> 8;
    int rem = rb & 255;
    int c0 = (rem >> 6) * 64;
    int n0 = (rem & 63) * 64;
    const float* src = fm + (size_t)b * CC * NN;
    float* dst = fm_t + (size_t)b * NN * CC;
    int tx = tid & 63, ty = tid >> 6;
    for (int r = ty; r < 64; r += 4)
      tile[r][tx] = src[(size_t)(c0 + r) * NN + n0 + tx];
    __syncthreads();
    for (int r = ty; r < 64; r += 4)
      dst[(size_t)(n0 + r) * CC + c0 + tx] = tile[tx][r];
  }
}

// ---------------------------------------------------------------------------
// PHASE 2: KNN only — 2048 blocks x 4 waves, one key point per wave.
__global__ __launch_bounds__(256) void phase2(
    const float* __restrict__ verts, const int* __restrict__ fpsi,
    int* __restrict__ knni) {
  __shared__ __align__(16) char smem[66560];
  int blk = blockIdx.x;
  int tid = threadIdx.x;
  int wave = tid >> 6, lane = tid & 63;
  int bm = blk * 4 + wave;
  int b = bm >> 10, m = bm & 1023;
  float* dbuf = (float*)smem + wave * (64 * 65);
  const float* vb = verts + (size_t)b * 3 * NN;
  int jm = fpsi[b * MM + m];
  float kx = vb[jm], ky = vb[NN + jm], kz = vb[2 * NN + jm];
  float kn = kx * kx + ky * ky + kz * kz;
  float v1 = INFINITY, v2 = INFINITY;
  int i1 = -1, i2 = -1;
  for (int t = 0; t < 64; ++t) {
    int j = t * 64 + lane;
    float x = vb[j], y = vb[NN + j], z = vb[2 * NN + j];
    float xn = x * x + y * y + z * z;
    float d = kn + xn - 2.0f * (kx * x + ky * y + kz * z);
    dbuf[lane * 65 + t] = d;
    if (d < v1) { v2 = v1; i2 = i1; v1 = d; i1 = j; }
    else if (d < v2) { v2 = d; i2 = j; }
  }
  for (int it = 0; it < KNB; ++it) {
    float rv = v1;
    int ri = i1;
#pragma unroll
    for (int off = 32; off >= 1; off >>= 1) {
      float ov = __shfl_down(rv, off, 64);
      int oi = __shfl_down(ri, off, 64);
      if (ov < rv || (ov == rv && oi < ri)) { rv = ov; ri = oi; }
    }
    ri = __shfl(ri, 0, 64);
    if (lane == 0) knni[(size_t)(b * MM + m) * KNB + it] = ri;
    if (i1 == ri) {
      dbuf[lane * 65 + (ri >> 6)] = INFINITY;
      v1 = v2; i1 = i2;
      v2 = INFINITY; i2 = -1;
      if (i1 < 0) {
        v1 = INFINITY; v2 = INFINITY; i1 = -1; i2 = -1;
        for (int t = 0; t < 64; ++t) {
          float d = dbuf[lane * 65 + t];
          int j = t * 64 + lane;
          if (d < v1) { v2 = v1; i2 = i1; v1 = d; i1 = j; }
          else if (d < v2) { v2 = d; i2 = j; }
        }
      }
    }
  }
}

// ---------------------------------------------------------------------------
// Fused per-(b,m). Stage D v2: per-thread weight columns are CONTIGUOUS rows
// of the ORIGINAL aw2/pw2 layouts -> 16 dwordx4 up-front register loads per
// loop, one vmcnt drain, zero per-iteration global latency. Accumulation
// order identical to previous round (bitwise-same output).
__global__ __launch_bounds__(256, 3) void fuse_kernel(
    const float* __restrict__ verts, const float* __restrict__ fm_t,
    const float* __restrict__ G2,
    const int* __restrict__ fpsi, const int* __restrict__ knni,
    const float* __restrict__ w1f, const float* __restrict__ b1f,
    const float* __restrict__ ab1f, const float* __restrict__ aw1t,
    const float* __restrict__ W12t, const float* __restrict__ pw2,
    const float* __restrict__ pb2, const float* __restrict__ aw2,
    const float* __restrict__ ab2, float* __restrict__ out) {
  int bm = blockIdx.x;
  int b = bm & 7, m = bm >> 3;  // batch -> XCD pinning
  int tid = threadIdx.x;

  __shared__ __attribute__((aligned(16))) float kfpb[256];
  __shared__ __attribute__((aligned(16))) float gp[3][16];
  __shared__ __attribute__((aligned(16))) float kp[4];
  __shared__ int kidx[16];
  __shared__ __attribute__((aligned(16))) float W12_l[64][68];
  __shared__ __attribute__((aligned(16))) float h_l[16][68];
  __shared__ __attribute__((aligned(16))) float hT_l[64][20];
  __shared__ __attribute__((aligned(16))) float h2T_l[64][20];
  __shared__ __attribute__((aligned(16))) float vmp[4][64];
  __shared__ __attribute__((aligned(16))) float vm_l[64];

  const float* vb = verts + (size_t)b * 3 * NN;
  const float* fb = fm_t + (size_t)b * NN * CC;
  int jm = fpsi[b * MM + m];
  float pbv = pb2[tid];  // held in register (was pb2_l LDS)
  if (tid < 16) kidx[tid] = knni[((size_t)b * MM + m) * 16 + tid];
  kfpb[tid] = fb[(size_t)jm * CC + tid] + pbv;
  if (tid < 3) kp[tid] = vb[tid * NN + jm];
  __syncthreads();

  if (tid < 48) {
    int c = tid >> 4, k = tid & 15;
    gp[c][k] = vb[c * NN + kidx[k]];
  }
  {
    int i = tid >> 4, d4 = tid & 15;
#pragma unroll
    for (int rep = 0; rep < 4; ++rep)
      *(float4*)&W12_l[i + rep * 16][d4 * 4] =
          *(const float4*)&W12t[(i + rep * 16) * 64 + d4 * 4];
  }
  {
    int d = tid & 63, part = tid >> 6;
    float acc = 0.f;
#pragma unroll 4
    for (int cc = 0; cc < 64; ++cc) {
      int c = part * 64 + cc;
      acc += aw1t[c * 64 + d] * kfpb[c];
    }
    vmp[part][d] = acc;
  }
  __syncthreads();
  if (tid < 64)
    vm_l[tid] = vmp[0][tid] + vmp[1][tid] + vmp[2][tid] + vmp[3][tid] + ab1f[tid];

  {
    int d = tid & 63, part = tid >> 6;
    float wd0 = w1f[d * 4 + 0], wd1 = w1f[d * 4 + 1], wd2 = w1f[d * 4 + 2];
    float bd = b1f[d];
#pragma unroll
    for (int j = 0; j < 4; ++j) {
      int k = part * 4 + j;
      float hv = wd0 * (kp[0] - gp[0][k]) + wd1 * (kp[1] - gp[1][k]) +
                 wd2 * (kp[2] - gp[2][k]) + bd;
      hv = (hv > 0.f) ? hv : 0.2f * hv;
      h_l[k][d] = hv;
      hT_l[d][k] = hv;
    }
  }
  __syncthreads();

  {
    int k = tid & 15, d2 = tid >> 4;
    float4 g4 = *(const float4*)&G2[((size_t)b * NN + kidx[k]) * 64 + d2 * 4];
    float a0 = 0.f, a1 = 0.f, a2 = 0.f, a3 = 0.f;
#pragma unroll 4
    for (int i = 0; i < 64; ++i) {
      float hv = h_l[k][i];
      float4 w4 = *(const float4*)&W12_l[i][d2 * 4];
      a0 += hv * w4.x; a1 += hv * w4.y; a2 += hv * w4.z; a3 += hv * w4.w;
    }
    float4 v4 = *(const float4*)&vm_l[d2 * 4];
    float r0 = v4.x - g4.x + a0;
    float r1 = v4.y - g4.y + a1;
    float r2 = v4.z - g4.z + a2;
    float r3 = v4.w - g4.w + a3;
    h2T_l[d2 * 4 + 0][k] = (r0 > 0.f) ? r0 : 0.2f * r0;
    h2T_l[d2 * 4 + 1][k] = (r1 > 0.f) ? r1 : 0.2f * r1;
    h2T_l[d2 * 4 + 2][k] = (r2 > 0.f) ? r2 : 0.2f * r2;
    h2T_l[d2 * 4 + 3][k] = (r3 > 0.f) ? r3 : 0.2f * r3;
  }
  __syncthreads();

  // Stage D, xyz channels first (register reuse): threads 0..2, o = tid.
  if (tid < 3) {
    float wcol[64];
    const float* wrow = aw2 + (size_t)tid * 64;
#pragma unroll
    for (int q = 0; q < 16; ++q)
      *(float4*)&wcol[q * 4] = *(const float4*)(wrow + q * 4);
    float lg[16];
    float bias = ab2[tid];
#pragma unroll
    for (int k = 0; k < 16; ++k) lg[k] = bias;
#pragma unroll 4
    for (int i = 0; i < 64; ++i) {
      float wv = wcol[i];
      float4 ha = *(const float4*)&h2T_l[i][0];
      float4 hb = *(const float4*)&h2T_l[i][4];
      float4 hc = *(const float4*)&h2T_l[i][8];
      float4 hd = *(const float4*)&h2T_l[i][12];
      lg[0] += wv * ha.x;  lg[1] += wv * ha.y;  lg[2] += wv * ha.z;  lg[3] += wv * ha.w;
      lg[4] += wv * hb.x;  lg[5] += wv * hb.y;  lg[6] += wv * hb.z;  lg[7] += wv * hb.w;
      lg[8] += wv * hc.x;  lg[9] += wv * hc.y;  lg[10] += wv * hc.z; lg[11] += wv * hc.w;
      lg[12] += wv * hd.x; lg[13] += wv * hd.y; lg[14] += wv * hd.z; lg[15] += wv * hd.w;
    }
    float mx = lg[0];
#pragma unroll
    for (int k = 1; k < 16; ++k) mx = fmaxf(mx, lg[k]);
    float sum = 0.f;
#pragma unroll
    for (int k = 0; k < 16; ++k) { lg[k] = __expf(lg[k] - mx); sum += lg[k]; }
    float inv = 1.f / sum;
    float a2 = 0.f;
#pragma unroll
    for (int k = 0; k < 16; ++k) a2 += lg[k] * gp[tid][k];
    out[((size_t)b * OC + tid) * MM + m] = a2 * inv;
  }

  // Stage D main: o = tid + 3 (c = tid).
  {
    int o = tid + 3;
    // --- up-front register loads: weight column (contiguous aw2 row) + gf
    float wcol[64];
    const float* wrow = aw2 + (size_t)o * 64;
#pragma unroll
    for (int q = 0; q < 16; ++q)
      *(float4*)&wcol[q * 4] = *(const float4*)(wrow + q * 4);
    float gfv[16];
#pragma unroll
    for (int k = 0; k < 16; ++k)
      gfv[k] = fb[(size_t)kidx[k] * CC + tid];
    float lg[16];
    float bias = ab2[o];
#pragma unroll
    for (int k = 0; k < 16; ++k) lg[k] = bias;
#pragma unroll 4
    for (int i = 0; i < 64; ++i) {
      float wv = wcol[i];
      float4 ha = *(const float4*)&h2T_l[i][0];
      float4 hb = *(const float4*)&h2T_l[i][4];
      float4 hc = *(const float4*)&h2T_l[i][8];
      float4 hd = *(const float4*)&h2T_l[i][12];
      lg[0] += wv * ha.x;  lg[1] += wv * ha.y;  lg[2] += wv * ha.z;  lg[3] += wv * ha.w;
      lg[4] += wv * hb.x;  lg[5] += wv * hb.y;  lg[6] += wv * hb.z;  lg[7] += wv * hb.w;
      lg[8] += wv * hc.x;  lg[9] += wv * hc.y;  lg[10] += wv * hc.z; lg[11] += wv * hc.w;
      lg[12] += wv * hd.x; lg[13] += wv * hd.y; lg[14] += wv * hd.z; lg[15] += wv * hd.w;
    }
    float mx = lg[0];
#pragma unroll
    for (int k = 1; k < 16; ++k) mx = fmaxf(mx, lg[k]);
    float sum = 0.f;
#pragma unroll
    for (int k = 0; k < 16; ++k) { lg[k] = __expf(lg[k] - mx); sum += lg[k]; }
    float inv = 1.f / sum;
#pragma unroll
    for (int k = 0; k < 16; ++k) lg[k] *= inv;  // lg = softmax weights now
    // --- pe column loads up-front (contiguous pw2 row for c = tid)
    float pcol[64];
    const float* prow = pw2 + (size_t)tid * 64;
#pragma unroll
    for (int q = 0; q < 16; ++q)
      *(float4*)&pcol[q * 4] = *(const float4*)(prow + q * 4);
    float acc = 0.f;
#pragma unroll
    for (int k = 0; k < 16; ++k) acc += lg[k] * gfv[k];
#pragma unroll 4
    for (int i = 0; i < 64; ++i) {
      float p = pcol[i];
      float4 ha = *(const float4*)&hT_l[i][0];
      float4 hb = *(const float4*)&hT_l[i][4];
      float4 hc = *(const float4*)&hT_l[i][8];
      float4 hd = *(const float4*)&hT_l[i][12];
      float hw = lg[0] * ha.x + lg[1] * ha.y + lg[2] * ha.z + lg[3] * ha.w +
                 lg[4] * hb.x + lg[5] * hb.y + lg[6] * hb.z + lg[7] * hb.w +
                 lg[8] * hc.x + lg[9] * hc.y + lg[10] * hc.z + lg[11] * hc.w +
                 lg[12] * hd.x + lg[13] * hd.y + lg[14] * hd.z + lg[15] * hd.w;
      acc += p * hw;
    }
    out[((size_t)b * OC + o) * MM + m] = pbv + acc;
  }
}

// ---------------------------------------------------------------------------
extern "C" void kernel_launch(void* const* d_in, const int* in_sizes, int n_in,
                              void* d_out, int out_size, void* d_ws, size_t ws_size,
                              hipStream_t stream) {
  (void)in_sizes; (void)n_in; (void)out_size; (void)ws_size;
  const float* verts = (const float*)d_in[0];
  const float* fm = (const float*)d_in[1];
  const float* pw1 = (const float*)d_in[2];
  const float* pb1 = (const float*)d_in[3];
  const float* g1 = (const float*)d_in[4];
  const float* bb1 = (const float*)d_in[5];
  const float* m1 = (const float*)d_in[6];
  const float* v1 = (const float*)d_in[7];
  const float* pw2 = (const float*)d_in[8];
  const float* pb2 = (const float*)d_in[9];
  const float* aw1 = (const float*)d_in[10];
  const float* ab1 = (const float*)d_in[11];
  const float* g2 = (const float*)d_in[12];
  const float* bb2 = (const float*)d_in[13];
  const float* m2 = (const float*)d_in[14];
  const float* v2 = (const float*)d_in[15];
  const float* aw2 = (const float*)d_in[16];
  const float* ab2 = (const float*)d_in[17];
  float* out = (float*)d_out;

  char* ws = (char*)d_ws;
  float* fm_t = (float*)ws;                               // 33,554,432 B
  float* G2 = (float*)(ws + 33554432);                    //  8,388,608 B
  int* fpsi = (int*)(ws + 41943040);                      //     32,768 B
  int* knni = (int*)(ws + 41975808);                      //    524,288 B
  float* w1f = (float*)(ws + 42500096);
  float* b1f = w1f + 256;
  float* ab1f = b1f + 64;
  float* aw1t = ab1f + 64;                                // 256*64
  float* W12t = aw1t + 256 * 64;                          // 64*64

  hipLaunchKernelGGL(phase1, dim3(2585), dim3(256), 0, stream,
                     verts, fm, pw1, pb1, g1, bb1, m1, v1, pw2, aw1, g2, bb2,
                     m2, v2, ab1,
                     fm_t, fpsi, G2, w1f, b1f, ab1f, aw1t, W12t);
  hipLaunchKernelGGL(phase2, dim3(2048), dim3(256), 0, stream,
                     verts, fpsi, knni);
  hipLaunchKernelGGL(fuse_kernel, dim3(8192), dim3(256), 0, stream,
                     verts, fm_t, G2, fpsi, knni, w1f, b1f, ab1f, aw1t, W12t,
                     pw2, pb2, aw2, ab2, out);
}

// Round 10
// 1241.212 us; speedup vs baseline: 1.1800x; 1.1800x over previous
//
#include <hip/hip_runtime.h>
#include <math.h>

#define BB 8
#define NN 4096
#define CC 256
#define DD 64
#define MM 1024
#define KNB 16
#define OC 259

typedef unsigned long long ull;

// ---------------------------------------------------------------------------
// PHASE 1: blk 0-7 FPS | 8-519 G2 GEMM (self-scaled aw1, no prep dep) |
// 520 prep | 521-536 W12 | 537-2584 transpose. fps dominates (~690us); all
// other roles run concurrently on the remaining CUs.
__global__ __launch_bounds__(256) void phase1(
    const float* __restrict__ verts, const float* __restrict__ fm,
    const float* __restrict__ pw1, const float* __restrict__ pb1,
    const float* __restrict__ g1, const float* __restrict__ bb1,
    const float* __restrict__ m1, const float* __restrict__ v1,
    const float* __restrict__ pw2, const float* __restrict__ aw1,
    const float* __restrict__ g2v, const float* __restrict__ bb2,
    const float* __restrict__ m2, const float* __restrict__ v2,
    const float* __restrict__ ab1,
    float* __restrict__ fm_t, int* __restrict__ fpsi, float* __restrict__ G2,
    float* __restrict__ w1f, float* __restrict__ b1f, float* __restrict__ ab1f,
    float* __restrict__ aw1t, float* __restrict__ W12t) {
  __shared__ __align__(16) char smem[53440];
  int blk = blockIdx.x;
  int tid = threadIdx.x;

  if (blk < 8) {
    // ---- FPS (verbatim proven version): 256 thr, 16 pts/thread,
    // reference-exact (p-c)^2 dist, two-pass DPP reduce, u64 parity slots,
    // depth-2 tree, no global stores in the loop.
    float* lx = (float*)smem;
    float* ly = lx + NN;
    float* lz = ly + NN;
    int* fps_l = (int*)(lz + NN);
    ull* wres = (ull*)(fps_l + MM);  // [2][4]
    int b = blk;
    const float* vb = verts + (size_t)b * 3 * NN;
    float px[16], py[16], pz[16], dist[16];
#pragma unroll
    for (int r = 0; r < 16; ++r) {
      int j = tid + r * 256;
      px[r] = vb[j]; py[r] = vb[NN + j]; pz[r] = vb[2 * NN + j];
      lx[j] = px[r]; ly[j] = py[r]; lz[j] = pz[r];
      dist[r] = 1e10f;
    }
    __syncthreads();
    int far = 0;
    for (int s = 0; s < MM; ++s) {
      if (tid == 0) fps_l[s] = far;
      if (s == MM - 1) break;
      float cx = lx[far], cy = ly[far], cz = lz[far];
      float vmax = -1.0f;
#pragma unroll
      for (int r = 0; r < 16; ++r) {
        float dx = px[r] - cx, dy = py[r] - cy, dz = pz[r] - cz;
        float d = dx * dx + dy * dy + dz * dz;
        dist[r] = fminf(dist[r], d);
        vmax = fmaxf(vmax, dist[r]);
      }
#define VRED(CTRL)                                                            \
      {                                                                       \
        int o = __builtin_amdgcn_update_dpp(__float_as_int(vmax),             \
                                            __float_as_int(vmax), CTRL, 0xF,  \
                                            0xF, false);                      \
        vmax = fmaxf(vmax, __int_as_float(o));                                \
      }
      VRED(0x111) VRED(0x112) VRED(0x114) VRED(0x118) VRED(0x142) VRED(0x143)
#undef VRED
      float svmax =
          __int_as_float(__builtin_amdgcn_readlane(__float_as_int(vmax), 63));
      int minj = 0x7FFFFFFF;
#pragma unroll
      for (int r = 0; r < 16; ++r) {
        int cand = (dist[r] == svmax) ? (tid + r * 256) : 0x7FFFFFFF;
        minj = (cand < minj) ? cand : minj;
      }
#define IRED(CTRL)                                                            \
      {                                                                       \
        int o = __builtin_amdgcn_update_dpp(minj, minj, CTRL, 0xF, 0xF,       \
                                            false);                          \
        minj = (o < minj) ? o : minj;                                         \
      }
      IRED(0x111) IRED(0x112) IRED(0x114) IRED(0x118) IRED(0x142) IRED(0x143)
#undef IRED
      if ((tid & 63) == 63)
        wres[(s & 1) * 4 + (tid >> 6)] =
            ((ull)(unsigned)__float_as_int(svmax) << 12) |
            (ull)(4095 - minj);
      __syncthreads();
      int p = s & 1;
      ull k0 = wres[p * 4 + 0], k1 = wres[p * 4 + 1];
      ull k2 = wres[p * 4 + 2], k3 = wres[p * 4 + 3];
      ull a = (k0 > k1) ? k0 : k1;
      ull c = (k2 > k3) ? k2 : k3;
      a = (c > a) ? c : a;
      far = 4095 - (int)(a & 0xFFFull);
    }
    __syncthreads();
    for (int x = tid; x < MM; x += 256) fpsi[b * MM + x] = fps_l[x];

  } else if (blk < 520) {
    // ---- G2[b][n][d] = sum_c (aw1[d][c]*s2[d]) * fm[b][c][n]
    float (*a_l)[68] = (float(*)[68])smem;
    float (*b_l)[68] = (float(*)[68])(smem + 64 * 68 * 4);
    int t = blk - 8;
    int b = t >> 6;
    int n0 = (t & 63) * 64;
    int rr = tid >> 4, q4 = tid & 15;
    float s2v[4];
#pragma unroll
    for (int j = 0; j < 4; ++j)
      s2v[j] = g2v[q4 * 4 + j] * rsqrtf(v2[q4 * 4 + j] + 1e-5f);
    float acc[4][4];
#pragma unroll
    for (int q = 0; q < 4; ++q)
#pragma unroll
      for (int x = 0; x < 4; ++x) acc[q][x] = 0.f;
    for (int c0 = 0; c0 < 256; c0 += 64) {
      __syncthreads();
#pragma unroll
      for (int rep = 0; rep < 4; ++rep) {
        int cc = rr + rep * 16;
        *(float4*)&a_l[cc][q4 * 4] =
            *(const float4*)&fm[((size_t)b * CC + c0 + cc) * NN + n0 + q4 * 4];
        float bv[4];
#pragma unroll
        for (int j = 0; j < 4; ++j)
          bv[j] = aw1[(q4 * 4 + j) * 256 + c0 + cc] * s2v[j];
        *(float4*)&b_l[cc][q4 * 4] = make_float4(bv[0], bv[1], bv[2], bv[3]);
      }
      __syncthreads();
#pragma unroll 8
      for (int kk = 0; kk < 64; ++kk) {
        float4 a4 = *(const float4*)&a_l[kk][rr * 4];
        float4 b4 = *(const float4*)&b_l[kk][q4 * 4];
        float av[4] = {a4.x, a4.y, a4.z, a4.w};
#pragma unroll
        for (int q = 0; q < 4; ++q) {
          acc[q][0] += av[q] * b4.x;
          acc[q][1] += av[q] * b4.y;
          acc[q][2] += av[q] * b4.z;
          acc[q][3] += av[q] * b4.w;
        }
      }
    }
#pragma unroll
    for (int q = 0; q < 4; ++q)
      *(float4*)&G2[((size_t)b * NN + n0 + rr * 4 + q) * 64 + q4 * 4] =
          make_float4(acc[q][0], acc[q][1], acc[q][2], acc[q][3]);

  } else if (blk == 520) {
    // ---- small weight prep (BN folds; aw1t for fuse's vm stage)
    if (tid < 64) {
      float s = g1[tid] * rsqrtf(v1[tid] + 1e-5f);
      w1f[tid * 4 + 0] = pw1[tid * 3 + 0] * s;
      w1f[tid * 4 + 1] = pw1[tid * 3 + 1] * s;
      w1f[tid * 4 + 2] = pw1[tid * 3 + 2] * s;
      w1f[tid * 4 + 3] = 0.f;
      b1f[tid] = (pb1[tid] - m1[tid]) * s + bb1[tid];
      float s2 = g2v[tid] * rsqrtf(v2[tid] + 1e-5f);
      ab1f[tid] = (ab1[tid] - m2[tid]) * s2 + bb2[tid];
    }
    for (int x = tid; x < 256 * 64; x += 256) {
      int c = x >> 6, d = x & 63;
      float s2 = g2v[d] * rsqrtf(v2[d] + 1e-5f);
      aw1t[x] = aw1[d * 256 + c] * s2;
    }

  } else if (blk < 537) {
    // ---- W12t[i][d] = sum_c pw2[c][i]*aw1[d][c]*s2[d]
    int i = tid & 63;
    int d = (blk - 521) * 4 + (tid >> 6);
    float s2 = g2v[d] * rsqrtf(v2[d] + 1e-5f);
    const float* arow = aw1 + d * 256;
    float s = 0.f;
#pragma unroll 4
    for (int c = 0; c < 256; ++c) s += pw2[c * 64 + i] * arow[c];
    W12t[i * 64 + d] = s * s2;

  } else {
    // ---- transpose feature_map (B,C,N) -> (B,N,C)
    float (*tile)[65] = (float(*)[65])smem;
    int rb = blk - 537;
    int b = rb >> 8;
    int rem = rb & 255;
    int c0 = (rem >> 6) * 64;
    int n0 = (rem & 63) * 64;
    const float* src = fm + (size_t)b * CC * NN;
    float* dst = fm_t + (size_t)b * NN * CC;
    int tx = tid & 63, ty = tid >> 6;
    for (int r = ty; r < 64; r += 4)
      tile[r][tx] = src[(size_t)(c0 + r) * NN + n0 + tx];
    __syncthreads();
    for (int r = ty; r < 64; r += 4)
      dst[(size_t)(n0 + r) * CC + c0 + tx] = tile[tx][r];
  }
}

// ---------------------------------------------------------------------------
// PHASE 2: KNN only — 2048 blocks x 4 waves, one key point per wave.
__global__ __launch_bounds__(256) void phase2(
    const float* __restrict__ verts, const int* __restrict__ fpsi,
    int* __restrict__ knni) {
  __shared__ __align__(16) char smem[66560];
  int blk = blockIdx.x;
  int tid = threadIdx.x;
  int wave = tid >> 6, lane = tid & 63;
  int bm = blk * 4 + wave;
  int b = bm >> 10, m = bm & 1023;
  float* dbuf = (float*)smem + wave * (64 * 65);
  const float* vb = verts + (size_t)b * 3 * NN;
  int jm = fpsi[b * MM + m];
  float kx = vb[jm], ky = vb[NN + jm], kz = vb[2 * NN + jm];
  float kn = kx * kx + ky * ky + kz * kz;
  float v1 = INFINITY, v2 = INFINITY;
  int i1 = -1, i2 = -1;
  for (int t = 0; t < 64; ++t) {
    int j = t * 64 + lane;
    float x = vb[j], y = vb[NN + j], z = vb[2 * NN + j];
    float xn = x * x + y * y + z * z;
    float d = kn + xn - 2.0f * (kx * x + ky * y + kz * z);
    dbuf[lane * 65 + t] = d;
    if (d < v1) { v2 = v1; i2 = i1; v1 = d; i1 = j; }
    else if (d < v2) { v2 = d; i2 = j; }
  }
  for (int it = 0; it < KNB; ++it) {
    float rv = v1;
    int ri = i1;
#pragma unroll
    for (int off = 32; off >= 1; off >>= 1) {
      float ov = __shfl_down(rv, off, 64);
      int oi = __shfl_down(ri, off, 64);
      if (ov < rv || (ov == rv && oi < ri)) { rv = ov; ri = oi; }
    }
    ri = __shfl(ri, 0, 64);
    if (lane == 0) knni[(size_t)(b * MM + m) * KNB + it] = ri;
    if (i1 == ri) {
      dbuf[lane * 65 + (ri >> 6)] = INFINITY;
      v1 = v2; i1 = i2;
      v2 = INFINITY; i2 = -1;
      if (i1 < 0) {
        v1 = INFINITY; v2 = INFINITY; i1 = -1; i2 = -1;
        for (int t = 0; t < 64; ++t) {
          float d = dbuf[lane * 65 + t];
          int j = t * 64 + lane;
          if (d < v1) { v2 = v1; i2 = i1; v1 = d; i1 = j; }
          else if (d < v2) { v2 = d; i2 = j; }
        }
      }
    }
  }
}

// ---------------------------------------------------------------------------
// Fused per-(b,m). Stage D v3: up-front float4 register loads (wc[16]/pc[16])
// with FULLY-unrolled compute loops -> all array indices compile-time
// constant (guaranteed VGPR residency; v2's partial unroll demoted the
// arrays to scratch — that was the round-9 regression).
__global__ __launch_bounds__(256, 3) void fuse_kernel(
    const float* __restrict__ verts, const float* __restrict__ fm_t,
    const float* __restrict__ G2,
    const int* __restrict__ fpsi, const int* __restrict__ knni,
    const float* __restrict__ w1f, const float* __restrict__ b1f,
    const float* __restrict__ ab1f, const float* __restrict__ aw1t,
    const float* __restrict__ W12t, const float* __restrict__ pw2,
    const float* __restrict__ pb2, const float* __restrict__ aw2,
    const float* __restrict__ ab2, float* __restrict__ out) {
  int bm = blockIdx.x;
  int b = bm & 7, m = bm >> 3;  // batch -> XCD pinning
  int tid = threadIdx.x;

  __shared__ __attribute__((aligned(16))) float kfpb[256];
  __shared__ __attribute__((aligned(16))) float gp[3][16];
  __shared__ __attribute__((aligned(16))) float kp[4];
  __shared__ int kidx[16];
  __shared__ __attribute__((aligned(16))) float W12_l[64][68];
  __shared__ __attribute__((aligned(16))) float h_l[16][68];
  __shared__ __attribute__((aligned(16))) float hT_l[64][20];
  __shared__ __attribute__((aligned(16))) float h2T_l[64][20];
  __shared__ __attribute__((aligned(16))) float vmp[4][64];
  __shared__ __attribute__((aligned(16))) float vm_l[64];

  const float* vb = verts + (size_t)b * 3 * NN;
  const float* fb = fm_t + (size_t)b * NN * CC;
  int jm = fpsi[b * MM + m];
  float pbv = pb2[tid];
  if (tid < 16) kidx[tid] = knni[((size_t)b * MM + m) * 16 + tid];
  kfpb[tid] = fb[(size_t)jm * CC + tid] + pbv;
  if (tid < 3) kp[tid] = vb[tid * NN + jm];
  __syncthreads();

  if (tid < 48) {
    int c = tid >> 4, k = tid & 15;
    gp[c][k] = vb[c * NN + kidx[k]];
  }
  {
    int i = tid >> 4, d4 = tid & 15;
#pragma unroll
    for (int rep = 0; rep < 4; ++rep)
      *(float4*)&W12_l[i + rep * 16][d4 * 4] =
          *(const float4*)&W12t[(i + rep * 16) * 64 + d4 * 4];
  }
  {
    int d = tid & 63, part = tid >> 6;
    float acc = 0.f;
#pragma unroll 4
    for (int cc = 0; cc < 64; ++cc) {
      int c = part * 64 + cc;
      acc += aw1t[c * 64 + d] * kfpb[c];
    }
    vmp[part][d] = acc;
  }
  __syncthreads();
  if (tid < 64)
    vm_l[tid] = vmp[0][tid] + vmp[1][tid] + vmp[2][tid] + vmp[3][tid] + ab1f[tid];

  {
    int d = tid & 63, part = tid >> 6;
    float wd0 = w1f[d * 4 + 0], wd1 = w1f[d * 4 + 1], wd2 = w1f[d * 4 + 2];
    float bd = b1f[d];
#pragma unroll
    for (int j = 0; j < 4; ++j) {
      int k = part * 4 + j;
      float hv = wd0 * (kp[0] - gp[0][k]) + wd1 * (kp[1] - gp[1][k]) +
                 wd2 * (kp[2] - gp[2][k]) + bd;
      hv = (hv > 0.f) ? hv : 0.2f * hv;
      h_l[k][d] = hv;
      hT_l[d][k] = hv;
    }
  }
  __syncthreads();

  {
    int k = tid & 15, d2 = tid >> 4;
    float4 g4 = *(const float4*)&G2[((size_t)b * NN + kidx[k]) * 64 + d2 * 4];
    float a0 = 0.f, a1 = 0.f, a2 = 0.f, a3 = 0.f;
#pragma unroll 4
    for (int i = 0; i < 64; ++i) {
      float hv = h_l[k][i];
      float4 w4 = *(const float4*)&W12_l[i][d2 * 4];
      a0 += hv * w4.x; a1 += hv * w4.y; a2 += hv * w4.z; a3 += hv * w4.w;
    }
    float4 v4 = *(const float4*)&vm_l[d2 * 4];
    float r0 = v4.x - g4.x + a0;
    float r1 = v4.y - g4.y + a1;
    float r2 = v4.z - g4.z + a2;
    float r3 = v4.w - g4.w + a3;
    h2T_l[d2 * 4 + 0][k] = (r0 > 0.f) ? r0 : 0.2f * r0;
    h2T_l[d2 * 4 + 1][k] = (r1 > 0.f) ? r1 : 0.2f * r1;
    h2T_l[d2 * 4 + 2][k] = (r2 > 0.f) ? r2 : 0.2f * r2;
    h2T_l[d2 * 4 + 3][k] = (r3 > 0.f) ? r3 : 0.2f * r3;
  }
  __syncthreads();

  // Stage D, xyz channels (3 lanes of wave 0; simple in-loop global loads).
  if (tid < 3) {
    float lg[16];
    float bias = ab2[tid];
#pragma unroll
    for (int k = 0; k < 16; ++k) lg[k] = bias;
    const float* wrow = aw2 + (size_t)tid * 64;
#pragma unroll 4
    for (int i = 0; i < 64; ++i) {
      float wv = wrow[i];
      float4 ha = *(const float4*)&h2T_l[i][0];
      float4 hb = *(const float4*)&h2T_l[i][4];
      float4 hc = *(const float4*)&h2T_l[i][8];
      float4 hd = *(const float4*)&h2T_l[i][12];
      lg[0] += wv * ha.x;  lg[1] += wv * ha.y;  lg[2] += wv * ha.z;  lg[3] += wv * ha.w;
      lg[4] += wv * hb.x;  lg[5] += wv * hb.y;  lg[6] += wv * hb.z;  lg[7] += wv * hb.w;
      lg[8] += wv * hc.x;  lg[9] += wv * hc.y;  lg[10] += wv * hc.z; lg[11] += wv * hc.w;
      lg[12] += wv * hd.x; lg[13] += wv * hd.y; lg[14] += wv * hd.z; lg[15] += wv * hd.w;
    }
    float mx = lg[0];
#pragma unroll
    for (int k = 1; k < 16; ++k) mx = fmaxf(mx, lg[k]);
    float sum = 0.f;
#pragma unroll
    for (int k = 0; k < 16; ++k) { lg[k] = __expf(lg[k] - mx); sum += lg[k]; }
    float inv = 1.f / sum;
    float a2 = 0.f;
#pragma unroll
    for (int k = 0; k < 16; ++k) a2 += lg[k] * gp[tid][k];
    out[((size_t)b * OC + tid) * MM + m] = a2 * inv;
  }

  // Stage D main: o = tid + 3 (c = tid). Fully-unrolled register version.
  {
    int o = tid + 3;
    float4 wc[16];
    const float* wrow = aw2 + (size_t)o * 64;
#pragma unroll
    for (int q = 0; q < 16; ++q)
      wc[q] = *(const float4*)(wrow + q * 4);
    float gfv[16];
#pragma unroll
    for (int k = 0; k < 16; ++k)
      gfv[k] = fb[(size_t)kidx[k] * CC + tid];
    float lg[16];
    float bias = ab2[o];
#pragma unroll
    for (int k = 0; k < 16; ++k) lg[k] = bias;
#pragma unroll
    for (int q = 0; q < 16; ++q) {
      float wv4[4] = {wc[q].x, wc[q].y, wc[q].z, wc[q].w};
#pragma unroll
      for (int j = 0; j < 4; ++j) {
        int i = q * 4 + j;
        float wv = wv4[j];
        float4 ha = *(const float4*)&h2T_l[i][0];
        float4 hb = *(const float4*)&h2T_l[i][4];
        float4 hc = *(const float4*)&h2T_l[i][8];
        float4 hd = *(const float4*)&h2T_l[i][12];
        lg[0] += wv * ha.x;  lg[1] += wv * ha.y;  lg[2] += wv * ha.z;  lg[3] += wv * ha.w;
        lg[4] += wv * hb.x;  lg[5] += wv * hb.y;  lg[6] += wv * hb.z;  lg[7] += wv * hb.w;
        lg[8] += wv * hc.x;  lg[9] += wv * hc.y;  lg[10] += wv * hc.z; lg[11] += wv * hc.w;
        lg[12] += wv * hd.x; lg[13] += wv * hd.y; lg[14] += wv * hd.z; lg[15] += wv * hd.w;
      }
    }
    float mx = lg[0];
#pragma unroll
    for (int k = 1; k < 16; ++k) mx = fmaxf(mx, lg[k]);
    float sum = 0.f;
#pragma unroll
    for (int k = 0; k < 16; ++k) { lg[k] = __expf(lg[k] - mx); sum += lg[k]; }
    float inv = 1.f / sum;
#pragma unroll
    for (int k = 0; k < 16; ++k) lg[k] *= inv;  // lg = softmax weights now
    float4 pc[16];
    const float* prow = pw2 + (size_t)tid * 64;
#pragma unroll
    for (int q = 0; q < 16; ++q)
      pc[q] = *(const float4*)(prow + q * 4);
    float acc = 0.f;
#pragma unroll
    for (int k = 0; k < 16; ++k) acc += lg[k] * gfv[k];
#pragma unroll
    for (int q = 0; q < 16; ++q) {
      float pv4[4] = {pc[q].x, pc[q].y, pc[q].z, pc[q].w};
#pragma unroll
      for (int j = 0; j < 4; ++j) {
        int i = q * 4 + j;
        float p = pv4[j];
        float4 ha = *(const float4*)&hT_l[i][0];
        float4 hb = *(const float4*)&hT_l[i][4];
        float4 hc = *(const float4*)&hT_l[i][8];
        float4 hd = *(const float4*)&hT_l[i][12];
        float hw = lg[0] * ha.x + lg[1] * ha.y + lg[2] * ha.z + lg[3] * ha.w +
                   lg[4] * hb.x + lg[5] * hb.y + lg[6] * hb.z + lg[7] * hb.w +
                   lg[8] * hc.x + lg[9] * hc.y + lg[10] * hc.z + lg[11] * hc.w +
                   lg[12] * hd.x + lg[13] * hd.y + lg[14] * hd.z + lg[15] * hd.w;
        acc += p * hw;
      }
    }
    out[((size_t)b * OC + o) * MM + m] = pbv + acc;
  }
}

// ---------------------------------------------------------------------------
extern "C" void kernel_launch(void* const* d_in, const int* in_sizes, int n_in,
                              void* d_out, int out_size, void* d_ws, size_t ws_size,
                              hipStream_t stream) {
  (void)in_sizes; (void)n_in; (void)out_size; (void)ws_size;
  const float* verts = (const float*)d_in[0];
  const float* fm = (const float*)d_in[1];
  const float* pw1 = (const float*)d_in[2];
  const float* pb1 = (const float*)d_in[3];
  const float* g1 = (const float*)d_in[4];
  const float* bb1 = (const float*)d_in[5];
  const float* m1 = (const float*)d_in[6];
  const float* v1 = (const float*)d_in[7];
  const float* pw2 = (const float*)d_in[8];
  const float* pb2 = (const float*)d_in[9];
  const float* aw1 = (const float*)d_in[10];
  const float* ab1 = (const float*)d_in[11];
  const float* g2 = (const float*)d_in[12];
  const float* bb2 = (const float*)d_in[13];
  const float* m2 = (const float*)d_in[14];
  const float* v2 = (const float*)d_in[15];
  const float* aw2 = (const float*)d_in[16];
  const float* ab2 = (const float*)d_in[17];
  float* out = (float*)d_out;

  char* ws = (char*)d_ws;
  float* fm_t = (float*)ws;                               // 33,554,432 B
  float* G2 = (float*)(ws + 33554432);                    //  8,388,608 B
  int* fpsi = (int*)(ws + 41943040);                      //     32,768 B
  int* knni = (int*)(ws + 41975808);                      //    524,288 B
  float* w1f = (float*)(ws + 42500096);
  float* b1f = w1f + 256;
  float* ab1f = b1f + 64;
  float* aw1t = ab1f + 64;                                // 256*64
  float* W12t = aw1t + 256 * 64;                          // 64*64

  hipLaunchKernelGGL(phase1, dim3(2585), dim3(256), 0, stream,
                     verts, fm, pw1, pb1, g1, bb1, m1, v1, pw2, aw1, g2, bb2,
                     m2, v2, ab1,
                     fm_t, fpsi, G2, w1f, b1f, ab1f, aw1t, W12t);
  hipLaunchKernelGGL(phase2, dim3(2048), dim3(256), 0, stream,
                     verts, fpsi, knni);
  hipLaunchKernelGGL(fuse_kernel, dim3(8192), dim3(256), 0, stream,
                     verts, fm_t, G2, fpsi, knni, w1f, b1f, ab1f, aw1t, W12t,
                     pw2, pb2, aw2, ab2, out);
}

// Round 11
// 1225.271 us; speedup vs baseline: 1.1954x; 1.0130x over previous
//
#include <hip/hip_runtime.h>
#include <math.h>

#define BB 8
#define NN 4096
#define CC 256
#define DD 64
#define MM 1024
#define KNB 16
#define OC 259

typedef unsigned long long ull;

// ---------------------------------------------------------------------------
// PHASE 1: blk 0-7 FPS | 8-519 G2 GEMM (self-scaled aw1, no prep dep) |
// 520 prep | 521-536 W12 | 537-2584 transpose. fps dominates (~690us); all
// other roles run concurrently on the remaining CUs.  (Proven; unchanged.)
__global__ __launch_bounds__(256) void phase1(
    const float* __restrict__ verts, const float* __restrict__ fm,
    const float* __restrict__ pw1, const float* __restrict__ pb1,
    const float* __restrict__ g1, const float* __restrict__ bb1,
    const float* __restrict__ m1, const float* __restrict__ v1,
    const float* __restrict__ pw2, const float* __restrict__ aw1,
    const float* __restrict__ g2v, const float* __restrict__ bb2,
    const float* __restrict__ m2, const float* __restrict__ v2,
    const float* __restrict__ ab1,
    float* __restrict__ fm_t, int* __restrict__ fpsi, float* __restrict__ G2,
    float* __restrict__ w1f, float* __restrict__ b1f, float* __restrict__ ab1f,
    float* __restrict__ aw1t, float* __restrict__ W12t) {
  __shared__ __align__(16) char smem[53440];
  int blk = blockIdx.x;
  int tid = threadIdx.x;

  if (blk < 8) {
    float* lx = (float*)smem;
    float* ly = lx + NN;
    float* lz = ly + NN;
    int* fps_l = (int*)(lz + NN);
    ull* wres = (ull*)(fps_l + MM);  // [2][4]
    int b = blk;
    const float* vb = verts + (size_t)b * 3 * NN;
    float px[16], py[16], pz[16], dist[16];
#pragma unroll
    for (int r = 0; r < 16; ++r) {
      int j = tid + r * 256;
      px[r] = vb[j]; py[r] = vb[NN + j]; pz[r] = vb[2 * NN + j];
      lx[j] = px[r]; ly[j] = py[r]; lz[j] = pz[r];
      dist[r] = 1e10f;
    }
    __syncthreads();
    int far = 0;
    for (int s = 0; s < MM; ++s) {
      if (tid == 0) fps_l[s] = far;
      if (s == MM - 1) break;
      float cx = lx[far], cy = ly[far], cz = lz[far];
      float vmax = -1.0f;
#pragma unroll
      for (int r = 0; r < 16; ++r) {
        float dx = px[r] - cx, dy = py[r] - cy, dz = pz[r] - cz;
        float d = dx * dx + dy * dy + dz * dz;
        dist[r] = fminf(dist[r], d);
        vmax = fmaxf(vmax, dist[r]);
      }
#define VRED(CTRL)                                                            \
      {                                                                       \
        int o = __builtin_amdgcn_update_dpp(__float_as_int(vmax),             \
                                            __float_as_int(vmax), CTRL, 0xF,  \
                                            0xF, false);                      \
        vmax = fmaxf(vmax, __int_as_float(o));                                \
      }
      VRED(0x111) VRED(0x112) VRED(0x114) VRED(0x118) VRED(0x142) VRED(0x143)
#undef VRED
      float svmax =
          __int_as_float(__builtin_amdgcn_readlane(__float_as_int(vmax), 63));
      int minj = 0x7FFFFFFF;
#pragma unroll
      for (int r = 0; r < 16; ++r) {
        int cand = (dist[r] == svmax) ? (tid + r * 256) : 0x7FFFFFFF;
        minj = (cand < minj) ? cand : minj;
      }
#define IRED(CTRL)                                                            \
      {                                                                       \
        int o = __builtin_amdgcn_update_dpp(minj, minj, CTRL, 0xF, 0xF,       \
                                            false);                          \
        minj = (o < minj) ? o : minj;                                         \
      }
      IRED(0x111) IRED(0x112) IRED(0x114) IRED(0x118) IRED(0x142) IRED(0x143)
#undef IRED
      if ((tid & 63) == 63)
        wres[(s & 1) * 4 + (tid >> 6)] =
            ((ull)(unsigned)__float_as_int(svmax) << 12) |
            (ull)(4095 - minj);
      __syncthreads();
      int p = s & 1;
      ull k0 = wres[p * 4 + 0], k1 = wres[p * 4 + 1];
      ull k2 = wres[p * 4 + 2], k3 = wres[p * 4 + 3];
      ull a = (k0 > k1) ? k0 : k1;
      ull c = (k2 > k3) ? k2 : k3;
      a = (c > a) ? c : a;
      far = 4095 - (int)(a & 0xFFFull);
    }
    __syncthreads();
    for (int x = tid; x < MM; x += 256) fpsi[b * MM + x] = fps_l[x];

  } else if (blk < 520) {
    float (*a_l)[68] = (float(*)[68])smem;
    float (*b_l)[68] = (float(*)[68])(smem + 64 * 68 * 4);
    int t = blk - 8;
    int b = t >> 6;
    int n0 = (t & 63) * 64;
    int rr = tid >> 4, q4 = tid & 15;
    float s2v[4];
#pragma unroll
    for (int j = 0; j < 4; ++j)
      s2v[j] = g2v[q4 * 4 + j] * rsqrtf(v2[q4 * 4 + j] + 1e-5f);
    float acc[4][4];
#pragma unroll
    for (int q = 0; q < 4; ++q)
#pragma unroll
      for (int x = 0; x < 4; ++x) acc[q][x] = 0.f;
    for (int c0 = 0; c0 < 256; c0 += 64) {
      __syncthreads();
#pragma unroll
      for (int rep = 0; rep < 4; ++rep) {
        int cc = rr + rep * 16;
        *(float4*)&a_l[cc][q4 * 4] =
            *(const float4*)&fm[((size_t)b * CC + c0 + cc) * NN + n0 + q4 * 4];
        float bv[4];
#pragma unroll
        for (int j = 0; j < 4; ++j)
          bv[j] = aw1[(q4 * 4 + j) * 256 + c0 + cc] * s2v[j];
        *(float4*)&b_l[cc][q4 * 4] = make_float4(bv[0], bv[1], bv[2], bv[3]);
      }
      __syncthreads();
#pragma unroll 8
      for (int kk = 0; kk < 64; ++kk) {
        float4 a4 = *(const float4*)&a_l[kk][rr * 4];
        float4 b4 = *(const float4*)&b_l[kk][q4 * 4];
        float av[4] = {a4.x, a4.y, a4.z, a4.w};
#pragma unroll
        for (int q = 0; q < 4; ++q) {
          acc[q][0] += av[q] * b4.x;
          acc[q][1] += av[q] * b4.y;
          acc[q][2] += av[q] * b4.z;
          acc[q][3] += av[q] * b4.w;
        }
      }
    }
#pragma unroll
    for (int q = 0; q < 4; ++q)
      *(float4*)&G2[((size_t)b * NN + n0 + rr * 4 + q) * 64 + q4 * 4] =
          make_float4(acc[q][0], acc[q][1], acc[q][2], acc[q][3]);

  } else if (blk == 520) {
    if (tid < 64) {
      float s = g1[tid] * rsqrtf(v1[tid] + 1e-5f);
      w1f[tid * 4 + 0] = pw1[tid * 3 + 0] * s;
      w1f[tid * 4 + 1] = pw1[tid * 3 + 1] * s;
      w1f[tid * 4 + 2] = pw1[tid * 3 + 2] * s;
      w1f[tid * 4 + 3] = 0.f;
      b1f[tid] = (pb1[tid] - m1[tid]) * s + bb1[tid];
      float s2 = g2v[tid] * rsqrtf(v2[tid] + 1e-5f);
      ab1f[tid] = (ab1[tid] - m2[tid]) * s2 + bb2[tid];
    }
    for (int x = tid; x < 256 * 64; x += 256) {
      int c = x >> 6, d = x & 63;
      float s2 = g2v[d] * rsqrtf(v2[d] + 1e-5f);
      aw1t[x] = aw1[d * 256 + c] * s2;
    }

  } else if (blk < 537) {
    int i = tid & 63;
    int d = (blk - 521) * 4 + (tid >> 6);
    float s2 = g2v[d] * rsqrtf(v2[d] + 1e-5f);
    const float* arow = aw1 + d * 256;
    float s = 0.f;
#pragma unroll 4
    for (int c = 0; c < 256; ++c) s += pw2[c * 64 + i] * arow[c];
    W12t[i * 64 + d] = s * s2;

  } else {
    float (*tile)[65] = (float(*)[65])smem;
    int rb = blk - 537;
    int b = rb >> 8;
    int rem = rb & 255;
    int c0 = (rem >> 6) * 64;
    int n0 = (rem & 63) * 64;
    const float* src = fm + (size_t)b * CC * NN;
    float* dst = fm_t + (size_t)b * NN * CC;
    int tx = tid & 63, ty = tid >> 6;
    for (int r = ty; r < 64; r += 4)
      tile[r][tx] = src[(size_t)(c0 + r) * NN + n0 + tx];
    __syncthreads();
    for (int r = ty; r < 64; r += 4)
      dst[(size_t)(n0 + r) * CC + c0 + tx] = tile[tx][r];
  }
}

// ---------------------------------------------------------------------------
// PHASE 2: KNN only — 2048 blocks x 4 waves, one key point per wave.
__global__ __launch_bounds__(256) void phase2(
    const float* __restrict__ verts, const int* __restrict__ fpsi,
    int* __restrict__ knni) {
  __shared__ __align__(16) char smem[66560];
  int blk = blockIdx.x;
  int tid = threadIdx.x;
  int wave = tid >> 6, lane = tid & 63;
  int bm = blk * 4 + wave;
  int b = bm >> 10, m = bm & 1023;
  float* dbuf = (float*)smem + wave * (64 * 65);
  const float* vb = verts + (size_t)b * 3 * NN;
  int jm = fpsi[b * MM + m];
  float kx = vb[jm], ky = vb[NN + jm], kz = vb[2 * NN + jm];
  float kn = kx * kx + ky * ky + kz * kz;
  float v1 = INFINITY, v2 = INFINITY;
  int i1 = -1, i2 = -1;
  for (int t = 0; t < 64; ++t) {
    int j = t * 64 + lane;
    float x = vb[j], y = vb[NN + j], z = vb[2 * NN + j];
    float xn = x * x + y * y + z * z;
    float d = kn + xn - 2.0f * (kx * x + ky * y + kz * z);
    dbuf[lane * 65 + t] = d;
    if (d < v1) { v2 = v1; i2 = i1; v1 = d; i1 = j; }
    else if (d < v2) { v2 = d; i2 = j; }
  }
  for (int it = 0; it < KNB; ++it) {
    float rv = v1;
    int ri = i1;
#pragma unroll
    for (int off = 32; off >= 1; off >>= 1) {
      float ov = __shfl_down(rv, off, 64);
      int oi = __shfl_down(ri, off, 64);
      if (ov < rv || (ov == rv && oi < ri)) { rv = ov; ri = oi; }
    }
    ri = __shfl(ri, 0, 64);
    if (lane == 0) knni[(size_t)(b * MM + m) * KNB + it] = ri;
    if (i1 == ri) {
      dbuf[lane * 65 + (ri >> 6)] = INFINITY;
      v1 = v2; i1 = i2;
      v2 = INFINITY; i2 = -1;
      if (i1 < 0) {
        v1 = INFINITY; v2 = INFINITY; i1 = -1; i2 = -1;
        for (int t = 0; t < 64; ++t) {
          float d = dbuf[lane * 65 + t];
          int j = t * 64 + lane;
          if (d < v1) { v2 = v1; i2 = i1; v1 = d; i1 = j; }
          else if (d < v2) { v2 = d; i2 = j; }
        }
      }
    }
  }
}

// ---------------------------------------------------------------------------
// Fused per-(b,m), v4: 128 threads; each thread owns TWO output columns
// (o = tid+3 and o = tid+131). Stage-D LDS b128 reads are shared across both
// columns -> LDS instruction count halved (round-10 showed LDS pipe, not
// global latency, is the binder: 16.8M ds_read_b128 ~= 218us floor).
// Per-column i-ascending accumulation order preserved.
__global__ __launch_bounds__(128, 2) void fuse_kernel(
    const float* __restrict__ verts, const float* __restrict__ fm_t,
    const float* __restrict__ G2,
    const int* __restrict__ fpsi, const int* __restrict__ knni,
    const float* __restrict__ w1f, const float* __restrict__ b1f,
    const float* __restrict__ ab1f, const float* __restrict__ aw1t,
    const float* __restrict__ W12t, const float* __restrict__ pw2,
    const float* __restrict__ pb2, const float* __restrict__ aw2,
    const float* __restrict__ ab2, float* __restrict__ out) {
  int bm = blockIdx.x;
  int b = bm & 7, m = bm >> 3;  // batch -> XCD pinning
  int tid = threadIdx.x;

  __shared__ __attribute__((aligned(16))) float kfpb[256];
  __shared__ __attribute__((aligned(16))) float gp[3][16];
  __shared__ __attribute__((aligned(16))) float kp[4];
  __shared__ int kidx[16];
  __shared__ __attribute__((aligned(16))) float W12_l[64][68];
  __shared__ __attribute__((aligned(16))) float h_l[16][68];
  __shared__ __attribute__((aligned(16))) float hT_l[64][20];
  __shared__ __attribute__((aligned(16))) float h2T_l[64][20];
  __shared__ __attribute__((aligned(16))) float vmp[2][64];
  __shared__ __attribute__((aligned(16))) float vm_l[64];

  const float* vb = verts + (size_t)b * 3 * NN;
  const float* fb = fm_t + (size_t)b * NN * CC;
  int jm = fpsi[b * MM + m];
  float pbv0 = pb2[tid], pbv1 = pb2[tid + 128];
  if (tid < 16) kidx[tid] = knni[((size_t)b * MM + m) * 16 + tid];
  kfpb[tid] = fb[(size_t)jm * CC + tid] + pbv0;
  kfpb[tid + 128] = fb[(size_t)jm * CC + tid + 128] + pbv1;
  if (tid < 3) kp[tid] = vb[tid * NN + jm];
  __syncthreads();

  if (tid < 48) {
    int c = tid >> 4, k = tid & 15;
    gp[c][k] = vb[c * NN + kidx[k]];
  }
  {
    int i = tid >> 4, d4 = tid & 15;
#pragma unroll
    for (int rep = 0; rep < 8; ++rep)
      *(float4*)&W12_l[i + rep * 8][d4 * 4] =
          *(const float4*)&W12t[(i + rep * 8) * 64 + d4 * 4];
  }
  {
    int d = tid & 63, part = tid >> 6;  // part in {0,1}
    float acc = 0.f;
#pragma unroll 4
    for (int cc = 0; cc < 128; ++cc) {
      int c = part * 128 + cc;
      acc += aw1t[c * 64 + d] * kfpb[c];
    }
    vmp[part][d] = acc;
  }
  __syncthreads();
  if (tid < 64) vm_l[tid] = vmp[0][tid] + vmp[1][tid] + ab1f[tid];

  // Stage A: h = lrelu(conv1(pos_rel)); 2 parts x 8 k each.
  {
    int d = tid & 63, part = tid >> 6;
    float wd0 = w1f[d * 4 + 0], wd1 = w1f[d * 4 + 1], wd2 = w1f[d * 4 + 2];
    float bd = b1f[d];
#pragma unroll
    for (int j = 0; j < 8; ++j) {
      int k = part * 8 + j;
      float hv = wd0 * (kp[0] - gp[0][k]) + wd1 * (kp[1] - gp[1][k]) +
                 wd2 * (kp[2] - gp[2][k]) + bd;
      hv = (hv > 0.f) ? hv : 0.2f * hv;
      h_l[k][d] = hv;
      hT_l[d][k] = hv;
    }
  }
  __syncthreads();

  // Stage C: thread (k = tid&15, dg = tid>>4 in [0,8)) -> d-quads dg, dg+8.
  {
    int k = tid & 15, dg = tid >> 4;
    const float* g2row = &G2[((size_t)b * NN + kidx[k]) * 64];
    float4 g4a = *(const float4*)(g2row + dg * 4);
    float4 g4b = *(const float4*)(g2row + (dg + 8) * 4);
    float a0 = 0.f, a1 = 0.f, a2 = 0.f, a3 = 0.f;
    float e0 = 0.f, e1 = 0.f, e2 = 0.f, e3 = 0.f;
#pragma unroll 4
    for (int i = 0; i < 64; ++i) {
      float hv = h_l[k][i];
      float4 w4a = *(const float4*)&W12_l[i][dg * 4];
      float4 w4b = *(const float4*)&W12_l[i][(dg + 8) * 4];
      a0 += hv * w4a.x; a1 += hv * w4a.y; a2 += hv * w4a.z; a3 += hv * w4a.w;
      e0 += hv * w4b.x; e1 += hv * w4b.y; e2 += hv * w4b.z; e3 += hv * w4b.w;
    }
    float4 v4a = *(const float4*)&vm_l[dg * 4];
    float4 v4b = *(const float4*)&vm_l[(dg + 8) * 4];
    float r0 = v4a.x - g4a.x + a0;
    float r1 = v4a.y - g4a.y + a1;
    float r2 = v4a.z - g4a.z + a2;
    float r3 = v4a.w - g4a.w + a3;
    float s0 = v4b.x - g4b.x + e0;
    float s1 = v4b.y - g4b.y + e1;
    float s2 = v4b.z - g4b.z + e2;
    float s3 = v4b.w - g4b.w + e3;
    h2T_l[dg * 4 + 0][k] = (r0 > 0.f) ? r0 : 0.2f * r0;
    h2T_l[dg * 4 + 1][k] = (r1 > 0.f) ? r1 : 0.2f * r1;
    h2T_l[dg * 4 + 2][k] = (r2 > 0.f) ? r2 : 0.2f * r2;
    h2T_l[dg * 4 + 3][k] = (r3 > 0.f) ? r3 : 0.2f * r3;
    h2T_l[(dg + 8) * 4 + 0][k] = (s0 > 0.f) ? s0 : 0.2f * s0;
    h2T_l[(dg + 8) * 4 + 1][k] = (s1 > 0.f) ? s1 : 0.2f * s1;
    h2T_l[(dg + 8) * 4 + 2][k] = (s2 > 0.f) ? s2 : 0.2f * s2;
    h2T_l[(dg + 8) * 4 + 3][k] = (s3 > 0.f) ? s3 : 0.2f * s3;
  }
  __syncthreads();

  // Stage D, xyz channels (3 lanes of wave 0).
  if (tid < 3) {
    float lg[16];
    float bias = ab2[tid];
#pragma unroll
    for (int k = 0; k < 16; ++k) lg[k] = bias;
    const float* wrow = aw2 + (size_t)tid * 64;
#pragma unroll 4
    for (int i = 0; i < 64; ++i) {
      float wv = wrow[i];
      float4 ha = *(const float4*)&h2T_l[i][0];
      float4 hb = *(const float4*)&h2T_l[i][4];
      float4 hc = *(const float4*)&h2T_l[i][8];
      float4 hd = *(const float4*)&h2T_l[i][12];
      lg[0] += wv * ha.x;  lg[1] += wv * ha.y;  lg[2] += wv * ha.z;  lg[3] += wv * ha.w;
      lg[4] += wv * hb.x;  lg[5] += wv * hb.y;  lg[6] += wv * hb.z;  lg[7] += wv * hb.w;
      lg[8] += wv * hc.x;  lg[9] += wv * hc.y;  lg[10] += wv * hc.z; lg[11] += wv * hc.w;
      lg[12] += wv * hd.x; lg[13] += wv * hd.y; lg[14] += wv * hd.z; lg[15] += wv * hd.w;
    }
    float mx = lg[0];
#pragma unroll
    for (int k = 1; k < 16; ++k) mx = fmaxf(mx, lg[k]);
    float sum = 0.f;
#pragma unroll
    for (int k = 0; k < 16; ++k) { lg[k] = __expf(lg[k] - mx); sum += lg[k]; }
    float inv = 1.f / sum;
    float a2 = 0.f;
#pragma unroll
    for (int k = 0; k < 16; ++k) a2 += lg[k] * gp[tid][k];
    out[((size_t)b * OC + tid) * MM + m] = a2 * inv;
  }

  // Stage D main: two columns per thread, shared h2T/hT reads.
  {
    int o0 = tid + 3, o1 = tid + 131;
    int c0 = tid, c1 = tid + 128;
    float gf0[16], gf1[16];
#pragma unroll
    for (int k = 0; k < 16; ++k) {
      const float* grow = fb + (size_t)kidx[k] * CC;
      gf0[k] = grow[c0];
      gf1[k] = grow[c1];
    }
    float lg0[16], lg1[16];
    float bias0 = ab2[o0], bias1 = ab2[o1];
#pragma unroll
    for (int k = 0; k < 16; ++k) { lg0[k] = bias0; lg1[k] = bias1; }
    const float* wr0 = aw2 + (size_t)o0 * 64;
    const float* wr1 = aw2 + (size_t)o1 * 64;
#pragma unroll
    for (int ch = 0; ch < 4; ++ch) {
      float4 wc0[4], wc1[4];
#pragma unroll
      for (int q = 0; q < 4; ++q) {
        wc0[q] = *(const float4*)(wr0 + ch * 16 + q * 4);
        wc1[q] = *(const float4*)(wr1 + ch * 16 + q * 4);
      }
#pragma unroll
      for (int q = 0; q < 4; ++q) {
        float w0v[4] = {wc0[q].x, wc0[q].y, wc0[q].z, wc0[q].w};
        float w1v[4] = {wc1[q].x, wc1[q].y, wc1[q].z, wc1[q].w};
#pragma unroll
        for (int j = 0; j < 4; ++j) {
          int i = ch * 16 + q * 4 + j;
          float wv0 = w0v[j], wv1 = w1v[j];
          float4 ha = *(const float4*)&h2T_l[i][0];
          float4 hb = *(const float4*)&h2T_l[i][4];
          float4 hc = *(const float4*)&h2T_l[i][8];
          float4 hd = *(const float4*)&h2T_l[i][12];
          lg0[0] += wv0 * ha.x;  lg0[1] += wv0 * ha.y;  lg0[2] += wv0 * ha.z;  lg0[3] += wv0 * ha.w;
          lg0[4] += wv0 * hb.x;  lg0[5] += wv0 * hb.y;  lg0[6] += wv0 * hb.z;  lg0[7] += wv0 * hb.w;
          lg0[8] += wv0 * hc.x;  lg0[9] += wv0 * hc.y;  lg0[10] += wv0 * hc.z; lg0[11] += wv0 * hc.w;
          lg0[12] += wv0 * hd.x; lg0[13] += wv0 * hd.y; lg0[14] += wv0 * hd.z; lg0[15] += wv0 * hd.w;
          lg1[0] += wv1 * ha.x;  lg1[1] += wv1 * ha.y;  lg1[2] += wv1 * ha.z;  lg1[3] += wv1 * ha.w;
          lg1[4] += wv1 * hb.x;  lg1[5] += wv1 * hb.y;  lg1[6] += wv1 * hb.z;  lg1[7] += wv1 * hb.w;
          lg1[8] += wv1 * hc.x;  lg1[9] += wv1 * hc.y;  lg1[10] += wv1 * hc.z; lg1[11] += wv1 * hc.w;
          lg1[12] += wv1 * hd.x; lg1[13] += wv1 * hd.y; lg1[14] += wv1 * hd.z; lg1[15] += wv1 * hd.w;
        }
      }
    }
    // softmax per column
    float mx0 = lg0[0], mx1 = lg1[0];
#pragma unroll
    for (int k = 1; k < 16; ++k) { mx0 = fmaxf(mx0, lg0[k]); mx1 = fmaxf(mx1, lg1[k]); }
    float sum0 = 0.f, sum1 = 0.f;
#pragma unroll
    for (int k = 0; k < 16; ++k) {
      lg0[k] = __expf(lg0[k] - mx0); sum0 += lg0[k];
      lg1[k] = __expf(lg1[k] - mx1); sum1 += lg1[k];
    }
    float inv0 = 1.f / sum0, inv1 = 1.f / sum1;
#pragma unroll
    for (int k = 0; k < 16; ++k) { lg0[k] *= inv0; lg1[k] *= inv1; }
    float acc0 = 0.f, acc1 = 0.f;
#pragma unroll
    for (int k = 0; k < 16; ++k) { acc0 += lg0[k] * gf0[k]; acc1 += lg1[k] * gf1[k]; }
    // pe aggregation, shared hT reads
    const float* pr0 = pw2 + (size_t)c0 * 64;
    const float* pr1 = pw2 + (size_t)c1 * 64;
#pragma unroll
    for (int ch = 0; ch < 4; ++ch) {
      float4 pc0[4], pc1[4];
#pragma unroll
      for (int q = 0; q < 4; ++q) {
        pc0[q] = *(const float4*)(pr0 + ch * 16 + q * 4);
        pc1[q] = *(const float4*)(pr1 + ch * 16 + q * 4);
      }
#pragma unroll
      for (int q = 0; q < 4; ++q) {
        float p0v[4] = {pc0[q].x, pc0[q].y, pc0[q].z, pc0[q].w};
        float p1v[4] = {pc1[q].x, pc1[q].y, pc1[q].z, pc1[q].w};
#pragma unroll
        for (int j = 0; j < 4; ++j) {
          int i = ch * 16 + q * 4 + j;
          float4 ha = *(const float4*)&hT_l[i][0];
          float4 hb = *(const float4*)&hT_l[i][4];
          float4 hc = *(const float4*)&hT_l[i][8];
          float4 hd = *(const float4*)&hT_l[i][12];
          float hw0 = lg0[0] * ha.x + lg0[1] * ha.y + lg0[2] * ha.z + lg0[3] * ha.w +
                      lg0[4] * hb.x + lg0[5] * hb.y + lg0[6] * hb.z + lg0[7] * hb.w +
                      lg0[8] * hc.x + lg0[9] * hc.y + lg0[10] * hc.z + lg0[11] * hc.w +
                      lg0[12] * hd.x + lg0[13] * hd.y + lg0[14] * hd.z + lg0[15] * hd.w;
          float hw1 = lg1[0] * ha.x + lg1[1] * ha.y + lg1[2] * ha.z + lg1[3] * ha.w +
                      lg1[4] * hb.x + lg1[5] * hb.y + lg1[6] * hb.z + lg1[7] * hb.w +
                      lg1[8] * hc.x + lg1[9] * hc.y + lg1[10] * hc.z + lg1[11] * hc.w +
                      lg1[12] * hd.x + lg1[13] * hd.y + lg1[14] * hd.z + lg1[15] * hd.w;
          acc0 += p0v[j] * hw0;
          acc1 += p1v[j] * hw1;
        }
      }
    }
    out[((size_t)b * OC + o0) * MM + m] = pbv0 + acc0;
    out[((size_t)b * OC + o1) * MM + m] = pbv1 + acc1;
  }
}

// ---------------------------------------------------------------------------
extern "C" void kernel_launch(void* const* d_in, const int* in_sizes, int n_in,
                              void* d_out, int out_size, void* d_ws, size_t ws_size,
                              hipStream_t stream) {
  (void)in_sizes; (void)n_in; (void)out_size; (void)ws_size;
  const float* verts = (const float*)d_in[0];
  const float* fm = (const float*)d_in[1];
  const float* pw1 = (const float*)d_in[2];
  const float* pb1 = (const float*)d_in[3];
  const float* g1 = (const float*)d_in[4];
  const float* bb1 = (const float*)d_in[5];
  const float* m1 = (const float*)d_in[6];
  const float* v1 = (const float*)d_in[7];
  const float* pw2 = (const float*)d_in[8];
  const float* pb2 = (const float*)d_in[9];
  const float* aw1 = (const float*)d_in[10];
  const float* ab1 = (const float*)d_in[11];
  const float* g2 = (const float*)d_in[12];
  const float* bb2 = (const float*)d_in[13];
  const float* m2 = (const float*)d_in[14];
  const float* v2 = (const float*)d_in[15];
  const float* aw2 = (const float*)d_in[16];
  const float* ab2 = (const float*)d_in[17];
  float* out = (float*)d_out;

  char* ws = (char*)d_ws;
  float* fm_t = (float*)ws;                               // 33,554,432 B
  float* G2 = (float*)(ws + 33554432);                    //  8,388,608 B
  int* fpsi = (int*)(ws + 41943040);                      //     32,768 B
  int* knni = (int*)(ws + 41975808);                      //    524,288 B
  float* w1f = (float*)(ws + 42500096);
  float* b1f = w1f + 256;
  float* ab1f = b1f + 64;
  float* aw1t = ab1f + 64;                                // 256*64
  float* W12t = aw1t + 256 * 64;                          // 64*64

  hipLaunchKernelGGL(phase1, dim3(2585), dim3(256), 0, stream,
                     verts, fm, pw1, pb1, g1, bb1, m1, v1, pw2, aw1, g2, bb2,
                     m2, v2, ab1,
                     fm_t, fpsi, G2, w1f, b1f, ab1f, aw1t, W12t);
  hipLaunchKernelGGL(phase2, dim3(2048), dim3(256), 0, stream,
                     verts, fpsi, knni);
  hipLaunchKernelGGL(fuse_kernel, dim3(8192), dim3(128), 0, stream,
                     verts, fm_t, G2, fpsi, knni, w1f, b1f, ab1f, aw1t, W12t,
                     pw2, pb2, aw2, ab2, out);
}